// Round 2
// baseline (267.466 us; speedup 1.0000x reference)
//
#include <hip/hip_runtime.h>

#define NBOND 96
#define HBS 158
#define NSTEP 288
#define NT 640

__global__ __launch_bounds__(NT, 1)
void gcn_mp_kernel(const int* __restrict__ a2b,
                   const int* __restrict__ b2a,
                   const int* __restrict__ b2revb,
                   const float* __restrict__ f_bonds,
                   const float* __restrict__ bond_sum,
                   const float* __restrict__ W0,
                   const float* __restrict__ b0,
                   const float* __restrict__ W1, const float* __restrict__ b1,
                   const float* __restrict__ W2, const float* __restrict__ b2v,
                   const float* __restrict__ W3, const float* __restrict__ b3,
                   const float* __restrict__ W4, const float* __restrict__ b4,
                   float* __restrict__ out)
{
  const int m = blockIdx.x;
  const int t = threadIdx.x;

  __shared__ __align__(16) float fb[NBOND * 160];   // rows padded to 160, cols 158/159 stay 0
  __shared__ __align__(16) float xv[320];           // [0:160)=fb[c], [160:320)=bs
  __shared__ float bss[160];
  __shared__ float hb1[112];
  __shared__ float hb2[72];
  __shared__ float hb3[40];
  __shared__ int sD[NSTEP];
  __shared__ int sR[NSTEP];
  __shared__ int sC[NSTEP];

  // ---- stage fb into LDS (pad cols >=158 with 0)
  for (int idx = t; idx < NBOND * 160; idx += NT) {
    int r = idx / 160, o = idx - r * 160;
    fb[idx] = (o < HBS) ? f_bonds[(m * NBOND + r) * HBS + o] : 0.f;
  }
  if (t < 160) bss[t] = (t < HBS) ? bond_sum[m * HBS + t] : 0.f;

  // ---- precompute per-step indices (data-independent addresses)
  if (t < NSTEP) {
    int i = t;
    int c = i / 3, j = i - c * 3;
    int a = b2a[m * NBOND + c];
    sD[i] = a2b[(m * NBOND + a) * 3 + j] - 1;   // d-1 in [0,96)
    sR[i] = b2revb[m * NBOND + c];
    sC[i] = c;
  }

  // ---- W0 fragment in registers: thread (o, kq) holds row o, K-slice [kq*80, kq*80+80)
  const int o  = t >> 2;    // 0..159
  const int kq = t & 3;     // 0..3
  float w[80];
#pragma unroll
  for (int kk = 0; kk < 80; ++kk) {
    const int k = kq * 80 + kk;                      // padded-K index, K=320
    const int col = (k < 160) ? k : (k - 2);         // [160,318) -> 158 + (k-160)
    const bool valid = (o < HBS) && ((k < 160) ? (k < HBS) : (k < 160 + HBS));
    w[kk] = valid ? W0[o * (2 * HBS) + col] : 0.f;
  }
  const float b0r = (kq == 0 && o < HBS) ? b0[o] : 0.f;

  __syncthreads();

  // ---- 288 sequential steps, 2 barriers each
#pragma unroll 1
  for (int i = 0; i < NSTEP; ++i) {
    const int c = sC[i];

    if (t < 160) {
      float b = bss[t] + fb[sD[i] * 160 + t] - fb[sR[i] * 160 + t];
      bss[t] = b;
      xv[160 + t] = b;                  // pads (158/159) stay 0 since fb pads are 0
    } else if (t < 320) {
      const int tt = t - 160;
      xv[tt] = fb[c * 160 + tt];
    }
    __syncthreads();

    float acc0 = 0.f, acc1 = 0.f, acc2 = 0.f, acc3 = 0.f;
    const float4* xq = (const float4*)(xv + kq * 80);
#pragma unroll
    for (int q = 0; q < 20; q += 4) {
      const float4 x0 = xq[q + 0];
      const float4 x1 = xq[q + 1];
      const float4 x2 = xq[q + 2];
      const float4 x3 = xq[q + 3];
      acc0 = fmaf(w[4*q + 0],  x0.x, acc0);
      acc0 = fmaf(w[4*q + 1],  x0.y, acc0);
      acc0 = fmaf(w[4*q + 2],  x0.z, acc0);
      acc0 = fmaf(w[4*q + 3],  x0.w, acc0);
      acc1 = fmaf(w[4*q + 4],  x1.x, acc1);
      acc1 = fmaf(w[4*q + 5],  x1.y, acc1);
      acc1 = fmaf(w[4*q + 6],  x1.z, acc1);
      acc1 = fmaf(w[4*q + 7],  x1.w, acc1);
      acc2 = fmaf(w[4*q + 8],  x2.x, acc2);
      acc2 = fmaf(w[4*q + 9],  x2.y, acc2);
      acc2 = fmaf(w[4*q + 10], x2.z, acc2);
      acc2 = fmaf(w[4*q + 11], x2.w, acc2);
      acc3 = fmaf(w[4*q + 12], x3.x, acc3);
      acc3 = fmaf(w[4*q + 13], x3.y, acc3);
      acc3 = fmaf(w[4*q + 14], x3.z, acc3);
      acc3 = fmaf(w[4*q + 15], x3.w, acc3);
    }
    float acc = (acc0 + acc1) + (acc2 + acc3);
    acc += __shfl_xor(acc, 1, 64);
    acc += __shfl_xor(acc, 2, 64);
    if (kq == 0) fb[c * 160 + o] = acc + b0r;   // rows 158/159 write 0 (w==0, b0r==0)
    __syncthreads();
  }

  // ---- mp = column sums of fb
  if (t < 160) {
    float s0 = 0.f, s1 = 0.f, s2 = 0.f, s3 = 0.f;
#pragma unroll
    for (int r = 0; r < NBOND; r += 4) {
      s0 += fb[(r + 0) * 160 + t];
      s1 += fb[(r + 1) * 160 + t];
      s2 += fb[(r + 2) * 160 + t];
      s3 += fb[(r + 3) * 160 + t];
    }
    xv[t] = (s0 + s1) + (s2 + s3);
  }
  __syncthreads();

  // ---- tiny MLP: 158 -> 110 (no relu) -> 70 (relu) -> 35 (relu) -> 1
  if (t < 110) {
    float acc = b1[t];
    for (int k = 0; k < HBS; ++k) acc = fmaf(xv[k], W1[t * HBS + k], acc);
    hb1[t] = acc;
  }
  __syncthreads();
  if (t < 70) {
    float acc = b2v[t];
    for (int k = 0; k < 110; ++k) acc = fmaf(hb1[k], W2[t * 110 + k], acc);
    hb2[t] = fmaxf(acc, 0.f);
  }
  __syncthreads();
  if (t < 35) {
    float acc = b3[t];
    for (int k = 0; k < 70; ++k) acc = fmaf(hb2[k], W3[t * 70 + k], acc);
    hb3[t] = fmaxf(acc, 0.f);
  }
  __syncthreads();
  if (t == 0) {
    float acc = b4[0];
    for (int k = 0; k < 35; ++k) acc = fmaf(hb3[k], W4[k], acc);
    out[m] = acc;
  }
}

extern "C" void kernel_launch(void* const* d_in, const int* in_sizes, int n_in,
                              void* d_out, int out_size, void* d_ws, size_t ws_size,
                              hipStream_t stream)
{
  const int*   a2b      = (const int*)d_in[0];
  const int*   b2a      = (const int*)d_in[1];
  const int*   b2revb   = (const int*)d_in[2];
  const float* f_bonds  = (const float*)d_in[3];
  /* d_in[4] = f_atoms_ (unused by forward) */
  const float* bond_sum = (const float*)d_in[5];
  const float* W0 = (const float*)d_in[6];
  const float* b0 = (const float*)d_in[7];
  const float* W1 = (const float*)d_in[8];
  const float* b1 = (const float*)d_in[9];
  const float* W2 = (const float*)d_in[10];
  const float* b2 = (const float*)d_in[11];
  const float* W3 = (const float*)d_in[12];
  const float* b3 = (const float*)d_in[13];
  const float* W4 = (const float*)d_in[14];
  const float* b4 = (const float*)d_in[15];

  gcn_mp_kernel<<<dim3(96), dim3(NT), 0, stream>>>(
      a2b, b2a, b2revb, f_bonds, bond_sum,
      W0, b0, W1, b1, W2, b2, W3, b3, W4, b4,
      (float*)d_out);
}